// Round 1
// baseline (685.100 us; speedup 1.0000x reference)
//
#include <hip/hip_runtime.h>
#include <math.h>

// Problem constants
#define B_  4
#define N_  170
#define T_  96
#define D_  256
#define H_  8
#define HD_ 32
#define R_  (B_*N_*T_)    // 65280 rows
#define G_  (B_*N_*H_)    // 5440 attention groups
#define QSZ (R_*D_)       // 16,711,680 floats per q/k/v buffer

// ---------------------------------------------------------------------------
// Kernel 1: fused Q/K/V projection.  out = X @ W^T + bias, written head-split:
// out[((bn*H + h)*T + t)*HD + hd],  row = bn*T + t, col = h*32 + hd.
// GEMM: M=65280, N=256, K=256.  BM=128, BN=128, BK=16, 256 thr, 8x8/thread.
// ---------------------------------------------------------------------------
#define PBM 128
#define PBN 128
#define PBK 16

__global__ __launch_bounds__(256)
void proj_kernel(const float* __restrict__ Xq, const float* __restrict__ Xk,
                 const float* __restrict__ Xv,
                 const float* __restrict__ Wq, const float* __restrict__ Wk,
                 const float* __restrict__ Wv,
                 const float* __restrict__ bq, const float* __restrict__ bk,
                 const float* __restrict__ bv,
                 float* __restrict__ oq, float* __restrict__ ok_,
                 float* __restrict__ ov)
{
    const int z = blockIdx.z;
    const float* X    = (z == 0) ? Xq : (z == 1) ? Xk : Xv;
    const float* W    = (z == 0) ? Wq : (z == 1) ? Wk : Wv;
    const float* bias = (z == 0) ? bq : (z == 1) ? bk : bv;
    float*       out  = (z == 0) ? oq : (z == 1) ? ok_ : ov;

    const int tid  = threadIdx.x;
    const int row0 = blockIdx.x * PBM;
    const int col0 = blockIdx.y * PBN;
    const int tx   = tid & 15;   // col group (16)
    const int ty   = tid >> 4;   // row group (16)

    // +4 pad: staging writes 2-way (free), a-frag conflict-free, b-frag 4-way
    __shared__ __align__(16) float As[PBK][PBM + 4];
    __shared__ __align__(16) float Bs[PBK][PBN + 4];

    float acc[8][8];
    #pragma unroll
    for (int i = 0; i < 8; i++)
        #pragma unroll
        for (int j = 0; j < 8; j++) acc[i][j] = 0.f;

    for (int k0 = 0; k0 < D_; k0 += PBK) {
        // stage A (128 rows x 16 k) and B (128 cols x 16 k): 2 float4 each/thread
        #pragma unroll
        for (int i = 0; i < 2; i++) {
            const int idx = tid + i * 256;
            const int r   = idx >> 2;
            const int kq  = (idx & 3) << 2;
            float4 a = *(const float4*)(X + (row0 + r) * D_ + k0 + kq);
            As[kq + 0][r] = a.x; As[kq + 1][r] = a.y;
            As[kq + 2][r] = a.z; As[kq + 3][r] = a.w;
            float4 b = *(const float4*)(W + (col0 + r) * D_ + k0 + kq);
            Bs[kq + 0][r] = b.x; Bs[kq + 1][r] = b.y;
            Bs[kq + 2][r] = b.z; Bs[kq + 3][r] = b.w;
        }
        __syncthreads();

        #pragma unroll
        for (int kk = 0; kk < PBK; kk++) {
            float4 a0 = *(const float4*)&As[kk][ty * 8];
            float4 a1 = *(const float4*)&As[kk][ty * 8 + 4];
            float4 b0 = *(const float4*)&Bs[kk][tx * 8];
            float4 b1 = *(const float4*)&Bs[kk][tx * 8 + 4];
            float a[8] = {a0.x, a0.y, a0.z, a0.w, a1.x, a1.y, a1.z, a1.w};
            float b[8] = {b0.x, b0.y, b0.z, b0.w, b1.x, b1.y, b1.z, b1.w};
            #pragma unroll
            for (int i = 0; i < 8; i++)
                #pragma unroll
                for (int j = 0; j < 8; j++)
                    acc[i][j] += a[i] * b[j];
        }
        __syncthreads();
    }

    // epilogue: bias + head-split store (8-col groups never cross a head boundary)
    #pragma unroll
    for (int i = 0; i < 8; i++) {
        const int rr = row0 + ty * 8 + i;
        const int bn = rr / T_;
        const int t  = rr - bn * T_;
        const int ccb = col0 + tx * 8;
        const int h   = ccb >> 5;
        const int hd0 = ccb & 31;
        float* op = out + ((bn * H_ + h) * T_ + t) * HD_ + hd0;
        float4 v0 = make_float4(acc[i][0] + bias[ccb + 0], acc[i][1] + bias[ccb + 1],
                                acc[i][2] + bias[ccb + 2], acc[i][3] + bias[ccb + 3]);
        float4 v1 = make_float4(acc[i][4] + bias[ccb + 4], acc[i][5] + bias[ccb + 5],
                                acc[i][6] + bias[ccb + 6], acc[i][7] + bias[ccb + 7]);
        *(float4*)(op)     = v0;
        *(float4*)(op + 4) = v1;
    }
}

// ---------------------------------------------------------------------------
// Kernel 2: attention per (bn, h) group. Mask == 1 exactly (softmax sums to 1),
// so plain softmax(QK^T/sqrt(32)) @ V.  256 threads/block, 5440 blocks.
// ---------------------------------------------------------------------------
__global__ __launch_bounds__(256)
void attn_kernel(const float* __restrict__ q, const float* __restrict__ k,
                 const float* __restrict__ v, float* __restrict__ ao)
{
    const int g   = blockIdx.x;          // g = bn*H + h
    const int tid = threadIdx.x;
    const float* Qg = q + (size_t)g * (T_ * HD_);
    const float* Kg = k + (size_t)g * (T_ * HD_);
    const float* Vg = v + (size_t)g * (T_ * HD_);

    __shared__ float Qt[HD_][T_ + 1];   // transposed [k][row], stride 97
    __shared__ float Kt[HD_][T_ + 1];
    __shared__ float Vs[T_][HD_ + 1];   // [key][hd], stride 33
    __shared__ float P [T_][T_ + 1];    // scores/probs, stride 97

    // load Q,K transposed; V direct. 768 float4 over 256 threads = 3 iters.
    #pragma unroll
    for (int it = 0; it < 3; it++) {
        const int idx = tid + it * 256;
        const int r   = idx >> 3;
        const int kq  = (idx & 7) << 2;
        float4 a = *(const float4*)(Qg + r * HD_ + kq);
        Qt[kq + 0][r] = a.x; Qt[kq + 1][r] = a.y;
        Qt[kq + 2][r] = a.z; Qt[kq + 3][r] = a.w;
        float4 b = *(const float4*)(Kg + r * HD_ + kq);
        Kt[kq + 0][r] = b.x; Kt[kq + 1][r] = b.y;
        Kt[kq + 2][r] = b.z; Kt[kq + 3][r] = b.w;
        float4 c = *(const float4*)(Vg + r * HD_ + kq);
        Vs[r][kq + 0] = c.x; Vs[r][kq + 1] = c.y;
        Vs[r][kq + 2] = c.z; Vs[r][kq + 3] = c.w;
    }
    __syncthreads();

    // scores: 16x16 thread grid, 6x6 tile per thread
    const int tx = tid & 15, ty = tid >> 4;
    const int r0 = ty * 6, c0 = tx * 6;
    {
        float s[6][6];
        #pragma unroll
        for (int i = 0; i < 6; i++)
            #pragma unroll
            for (int j = 0; j < 6; j++) s[i][j] = 0.f;

        for (int kk = 0; kk < HD_; kk++) {
            float qv[6], kv[6];
            #pragma unroll
            for (int i = 0; i < 6; i++) qv[i] = Qt[kk][r0 + i];
            #pragma unroll
            for (int j = 0; j < 6; j++) kv[j] = Kt[kk][c0 + j];
            #pragma unroll
            for (int i = 0; i < 6; i++)
                #pragma unroll
                for (int j = 0; j < 6; j++)
                    s[i][j] += qv[i] * kv[j];
        }
        const float scale = 0.17677669529663687f;  // 1/sqrt(32)
        #pragma unroll
        for (int i = 0; i < 6; i++)
            #pragma unroll
            for (int j = 0; j < 6; j++)
                P[r0 + i][c0 + j] = s[i][j] * scale;
    }
    __syncthreads();

    // softmax: one wave per row, 4 waves
    {
        const int wid = tid >> 6, lane = tid & 63;
        for (int r = wid; r < T_; r += 4) {
            float x0 = P[r][lane];
            float x1 = (lane < 32) ? P[r][64 + lane] : -INFINITY;
            float m = fmaxf(x0, x1);
            #pragma unroll
            for (int off = 32; off > 0; off >>= 1) m = fmaxf(m, __shfl_xor(m, off));
            float e0 = expf(x0 - m);
            float e1 = (lane < 32) ? expf(x1 - m) : 0.f;
            float ssum = e0 + e1;
            #pragma unroll
            for (int off = 32; off > 0; off >>= 1) ssum += __shfl_xor(ssum, off);
            float inv = 1.0f / ssum;
            P[r][lane] = e0 * inv;
            if (lane < 32) P[r][64 + lane] = e1 * inv;
        }
    }
    __syncthreads();

    // O = P @ V : 16x16 grid, 6 rows x 2 cols per thread
    {
        float o[6][2];
        #pragma unroll
        for (int i = 0; i < 6; i++) { o[i][0] = 0.f; o[i][1] = 0.f; }
        const int c2 = tx * 2;
        for (int kk = 0; kk < T_; kk++) {
            float v0 = Vs[kk][c2], v1 = Vs[kk][c2 + 1];
            #pragma unroll
            for (int i = 0; i < 6; i++) {
                float p = P[r0 + i][kk];
                o[i][0] += p * v0;
                o[i][1] += p * v1;
            }
        }
        const int bn = g >> 3, h = g & 7;
        float* aob = ao + ((size_t)bn * T_) * D_ + h * HD_;
        #pragma unroll
        for (int i = 0; i < 6; i++) {
            aob[(r0 + i) * D_ + c2 + 0] = o[i][0];
            aob[(r0 + i) * D_ + c2 + 1] = o[i][1];
        }
    }
}

// ---------------------------------------------------------------------------
// Kernel 3: out = out @ Wo^T + bo, IN-PLACE on d_out.
// BM=64, BN=256 (full width): each block reads only the rows it writes, and
// all global reads finish before the epilogue -> in-place is race-free.
// ---------------------------------------------------------------------------
#define OBM 64
#define OBN 256
#define OBK 16

__global__ __launch_bounds__(256)
void wo_kernel(const float* __restrict__ Wo, const float* __restrict__ bo,
               float* __restrict__ io)
{
    const int tid  = threadIdx.x;
    const int row0 = blockIdx.x * OBM;
    const int tx = tid >> 3;   // 0..31 col groups (x8 = 256)
    const int ty = tid & 7;    // 0..7 row groups (x8 = 64)

    __shared__ __align__(16) float As[OBK][OBM + 4];    // stride 68
    __shared__ __align__(16) float Bs[OBK][OBN + 4];    // stride 260

    float acc[8][8];
    #pragma unroll
    for (int i = 0; i < 8; i++)
        #pragma unroll
        for (int j = 0; j < 8; j++) acc[i][j] = 0.f;

    for (int k0 = 0; k0 < D_; k0 += OBK) {
        {   // A: 64x16 = 256 float4, 1/thread
            const int r  = tid >> 2;
            const int kq = (tid & 3) << 2;
            float4 a = *(const float4*)(io + (row0 + r) * D_ + k0 + kq);
            As[kq + 0][r] = a.x; As[kq + 1][r] = a.y;
            As[kq + 2][r] = a.z; As[kq + 3][r] = a.w;
        }
        #pragma unroll
        for (int i = 0; i < 4; i++) {   // B: 256x16 = 1024 float4, 4/thread
            const int idx = tid + i * 256;
            const int c   = idx >> 2;
            const int kq  = (idx & 3) << 2;
            float4 b = *(const float4*)(Wo + c * D_ + k0 + kq);
            Bs[kq + 0][c] = b.x; Bs[kq + 1][c] = b.y;
            Bs[kq + 2][c] = b.z; Bs[kq + 3][c] = b.w;
        }
        __syncthreads();

        #pragma unroll
        for (int kk = 0; kk < OBK; kk++) {
            float4 a0 = *(const float4*)&As[kk][ty * 8];
            float4 a1 = *(const float4*)&As[kk][ty * 8 + 4];
            float4 b0 = *(const float4*)&Bs[kk][tx * 8];
            float4 b1 = *(const float4*)&Bs[kk][tx * 8 + 4];
            float a[8] = {a0.x, a0.y, a0.z, a0.w, a1.x, a1.y, a1.z, a1.w};
            float b[8] = {b0.x, b0.y, b0.z, b0.w, b1.x, b1.y, b1.z, b1.w};
            #pragma unroll
            for (int i = 0; i < 8; i++)
                #pragma unroll
                for (int j = 0; j < 8; j++)
                    acc[i][j] += a[i] * b[j];
        }
        __syncthreads();
    }

    #pragma unroll
    for (int i = 0; i < 8; i++) {
        const int rr = row0 + ty * 8 + i;
        const int cc = tx * 8;
        float* op = io + rr * D_ + cc;
        float4 v0 = make_float4(acc[i][0] + bo[cc + 0], acc[i][1] + bo[cc + 1],
                                acc[i][2] + bo[cc + 2], acc[i][3] + bo[cc + 3]);
        float4 v1 = make_float4(acc[i][4] + bo[cc + 4], acc[i][5] + bo[cc + 5],
                                acc[i][6] + bo[cc + 6], acc[i][7] + bo[cc + 7]);
        *(float4*)(op)     = v0;
        *(float4*)(op + 4) = v1;
    }
}

// ---------------------------------------------------------------------------
extern "C" void kernel_launch(void* const* d_in, const int* in_sizes, int n_in,
                              void* d_out, int out_size, void* d_ws, size_t ws_size,
                              hipStream_t stream)
{
    const float* query = (const float*)d_in[0];
    const float* key   = (const float*)d_in[1];
    const float* value = (const float*)d_in[2];
    // d_in[3..5]: pattern_matrix, Wp, bp -- mathematically a no-op (mask == 1)
    const float* Wq = (const float*)d_in[6];
    const float* bq = (const float*)d_in[7];
    const float* Wk = (const float*)d_in[8];
    const float* bk = (const float*)d_in[9];
    const float* Wv = (const float*)d_in[10];
    const float* bv = (const float*)d_in[11];
    const float* Wo = (const float*)d_in[12];
    const float* bo = (const float*)d_in[13];

    float* out = (float*)d_out;
    float* ws  = (float*)d_ws;
    float* qb  = ws;               // head-split (bn,h,t,hd)
    float* kb  = ws + (size_t)QSZ;
    float* vb  = ws + (size_t)QSZ * 2;   // needs 200.5 MB of ws

    proj_kernel<<<dim3(R_ / PBM, D_ / PBN, 3), 256, 0, stream>>>(
        query, key, value, Wq, Wk, Wv, bq, bk, bv, qb, kb, vb);
    attn_kernel<<<dim3(G_), 256, 0, stream>>>(qb, kb, vb, out);
    wo_kernel<<<dim3(R_ / OBM), 256, 0, stream>>>(Wo, bo, out);
}

// Round 2
// 488.715 us; speedup vs baseline: 1.4018x; 1.4018x over previous
//
#include <hip/hip_runtime.h>
#include <math.h>

// Problem constants
#define B_  4
#define N_  170
#define T_  96
#define D_  256
#define H_  8
#define HD_ 32
#define R_  (B_*N_*T_)    // 65280 rows
#define G_  (B_*N_*H_)    // 5440 attention groups
#define QSZ (R_*D_)       // 16,711,680 floats per q/k/v buffer

typedef short bf16x8 __attribute__((ext_vector_type(8)));
typedef float f32x4  __attribute__((ext_vector_type(4)));

// split one fp32 pair into packed bf16 hi-word and lo-word (element0 in low 16)
// hi = truncate(x) (x - hi exact); lo = truncate(x - hi).  Dropped error ~2^-16.
__device__ __forceinline__ void split2(float x0, float x1, uint& hi, uint& lo)
{
    uint u0 = __builtin_bit_cast(uint, x0);
    uint u1 = __builtin_bit_cast(uint, x1);
    hi = (u0 >> 16) | (u1 & 0xFFFF0000u);
    float h0 = __builtin_bit_cast(float, u0 & 0xFFFF0000u);
    float h1 = __builtin_bit_cast(float, u1 & 0xFFFF0000u);
    float l0 = x0 - h0, l1 = x1 - h1;
    uint v0 = __builtin_bit_cast(uint, l0);
    uint v1 = __builtin_bit_cast(uint, l1);
    lo = (v0 >> 16) | (v1 & 0xFFFF0000u);
}

__device__ __forceinline__ void split8(float4 a0, float4 a1, uint4& hi, uint4& lo)
{
    split2(a0.x, a0.y, hi.x, lo.x);
    split2(a0.z, a0.w, hi.y, lo.y);
    split2(a1.x, a1.y, hi.z, lo.z);
    split2(a1.z, a1.w, hi.w, lo.w);
}

// ---------------------------------------------------------------------------
// Kernel 1: fused Q/K/V projection via split-bf16 MFMA.
// C = X @ W^T + bias, head-split store. M=65280, N=256, K=256.
// BM=128, BN=128, BK=32, 256 thr = 4 waves (2x2), 64x64 per wave.
// LDS frag layout [kg][row][8] -> conflict-free ds_read_b128.
// ---------------------------------------------------------------------------
__global__ __launch_bounds__(256)
void proj_kernel(const float* __restrict__ Xq, const float* __restrict__ Xk,
                 const float* __restrict__ Xv,
                 const float* __restrict__ Wq, const float* __restrict__ Wk,
                 const float* __restrict__ Wv,
                 const float* __restrict__ bq, const float* __restrict__ bk,
                 const float* __restrict__ bv,
                 float* __restrict__ oq, float* __restrict__ ok_,
                 float* __restrict__ ov)
{
    const int z = blockIdx.z;
    const float* X    = (z == 0) ? Xq : (z == 1) ? Xk : Xv;
    const float* W    = (z == 0) ? Wq : (z == 1) ? Wk : Wv;
    const float* bias = (z == 0) ? bq : (z == 1) ? bk : bv;
    float*       out  = (z == 0) ? oq : (z == 1) ? ok_ : ov;

    const int tid  = threadIdx.x;
    const int row0 = blockIdx.x * 128;
    const int col0 = blockIdx.y * 128;
    const int lane = tid & 63;
    const int w    = tid >> 6;        // wave id
    const int wr   = w >> 1;          // wave row (0..1)
    const int wc   = w & 1;           // wave col (0..1)
    const int lr   = lane & 15;       // row/col within fragment
    const int kgl  = lane >> 4;       // k-group 0..3

    // [kg][row][8 bf16] as uint4-addressable uints; 8 KB each
    __shared__ __align__(16) uint Ah[4*128*4];
    __shared__ __align__(16) uint Al[4*128*4];
    __shared__ __align__(16) uint Bh[4*128*4];
    __shared__ __align__(16) uint Bl[4*128*4];

    f32x4 acc[4][4];
    #pragma unroll
    for (int m = 0; m < 4; m++)
        #pragma unroll
        for (int n = 0; n < 4; n++) acc[m][n] = (f32x4)0.f;

    for (int k0 = 0; k0 < D_; k0 += 32) {
        // stage: 512 chunks each for A and B; 2 chunks/thread each
        #pragma unroll
        for (int i = 0; i < 2; i++) {
            const int c  = tid + i * 256;
            const int kg = c >> 7;
            const int r  = c & 127;
            const float* pa = X + (size_t)(row0 + r) * D_ + k0 + kg * 8;
            float4 a0 = *(const float4*)pa;
            float4 a1 = *(const float4*)(pa + 4);
            uint4 h, l;
            split8(a0, a1, h, l);
            *(uint4*)&Ah[(kg*128 + r)*4] = h;
            *(uint4*)&Al[(kg*128 + r)*4] = l;
            const float* pb = W + (size_t)(col0 + r) * D_ + k0 + kg * 8;
            float4 b0 = *(const float4*)pb;
            float4 b1 = *(const float4*)(pb + 4);
            split8(b0, b1, h, l);
            *(uint4*)&Bh[(kg*128 + r)*4] = h;
            *(uint4*)&Bl[(kg*128 + r)*4] = l;
        }
        __syncthreads();

        bf16x8 ah[4], al[4], bh[4], bl[4];
        #pragma unroll
        for (int m = 0; m < 4; m++) {
            const int ra = wr*64 + m*16 + lr;
            ah[m] = *(const bf16x8*)&Ah[(kgl*128 + ra)*4];
            al[m] = *(const bf16x8*)&Al[(kgl*128 + ra)*4];
        }
        #pragma unroll
        for (int n = 0; n < 4; n++) {
            const int cb = wc*64 + n*16 + lr;
            bh[n] = *(const bf16x8*)&Bh[(kgl*128 + cb)*4];
            bl[n] = *(const bf16x8*)&Bl[(kgl*128 + cb)*4];
        }
        #pragma unroll
        for (int m = 0; m < 4; m++)
            #pragma unroll
            for (int n = 0; n < 4; n++) {
                acc[m][n] = __builtin_amdgcn_mfma_f32_16x16x32_bf16(ah[m], bl[n], acc[m][n], 0, 0, 0);
                acc[m][n] = __builtin_amdgcn_mfma_f32_16x16x32_bf16(al[m], bh[n], acc[m][n], 0, 0, 0);
                acc[m][n] = __builtin_amdgcn_mfma_f32_16x16x32_bf16(ah[m], bh[n], acc[m][n], 0, 0, 0);
            }
        __syncthreads();
    }

    // epilogue: bias + head-split store. C/D: col=lane&15, row=(lane>>4)*4+reg
    #pragma unroll
    for (int n = 0; n < 4; n++) {
        const int gcol = col0 + wc*64 + n*16 + lr;
        const int h    = gcol >> 5;
        const int hd   = gcol & 31;
        const float bv = bias[gcol];
        #pragma unroll
        for (int m = 0; m < 4; m++) {
            #pragma unroll
            for (int reg = 0; reg < 4; reg++) {
                const int grow = row0 + wr*64 + m*16 + kgl*4 + reg;
                const int bn = grow / T_;
                const int t  = grow - bn * T_;
                out[((bn * H_ + h) * T_ + t) * HD_ + hd] = acc[m][n][reg] + bv;
            }
        }
    }
}

// ---------------------------------------------------------------------------
// Kernel 2: attention per (bn, h) group (mask == 1 exactly). fp32 vector.
// ---------------------------------------------------------------------------
__global__ __launch_bounds__(256)
void attn_kernel(const float* __restrict__ q, const float* __restrict__ k,
                 const float* __restrict__ v, float* __restrict__ ao)
{
    const int g   = blockIdx.x;          // g = bn*H + h
    const int tid = threadIdx.x;
    const float* Qg = q + (size_t)g * (T_ * HD_);
    const float* Kg = k + (size_t)g * (T_ * HD_);
    const float* Vg = v + (size_t)g * (T_ * HD_);

    __shared__ float Qt[HD_][T_ + 1];
    __shared__ float Kt[HD_][T_ + 1];
    __shared__ float Vs[T_][HD_ + 1];
    __shared__ float P [T_][T_ + 1];

    #pragma unroll
    for (int it = 0; it < 3; it++) {
        const int idx = tid + it * 256;
        const int r   = idx >> 3;
        const int kq  = (idx & 7) << 2;
        float4 a = *(const float4*)(Qg + r * HD_ + kq);
        Qt[kq + 0][r] = a.x; Qt[kq + 1][r] = a.y;
        Qt[kq + 2][r] = a.z; Qt[kq + 3][r] = a.w;
        float4 b = *(const float4*)(Kg + r * HD_ + kq);
        Kt[kq + 0][r] = b.x; Kt[kq + 1][r] = b.y;
        Kt[kq + 2][r] = b.z; Kt[kq + 3][r] = b.w;
        float4 c = *(const float4*)(Vg + r * HD_ + kq);
        Vs[r][kq + 0] = c.x; Vs[r][kq + 1] = c.y;
        Vs[r][kq + 2] = c.z; Vs[r][kq + 3] = c.w;
    }
    __syncthreads();

    const int tx = tid & 15, ty = tid >> 4;
    const int r0 = ty * 6, c0 = tx * 6;
    {
        float s[6][6];
        #pragma unroll
        for (int i = 0; i < 6; i++)
            #pragma unroll
            for (int j = 0; j < 6; j++) s[i][j] = 0.f;

        for (int kk = 0; kk < HD_; kk++) {
            float qv[6], kv[6];
            #pragma unroll
            for (int i = 0; i < 6; i++) qv[i] = Qt[kk][r0 + i];
            #pragma unroll
            for (int j = 0; j < 6; j++) kv[j] = Kt[kk][c0 + j];
            #pragma unroll
            for (int i = 0; i < 6; i++)
                #pragma unroll
                for (int j = 0; j < 6; j++)
                    s[i][j] += qv[i] * kv[j];
        }
        const float scale = 0.17677669529663687f;  // 1/sqrt(32)
        #pragma unroll
        for (int i = 0; i < 6; i++)
            #pragma unroll
            for (int j = 0; j < 6; j++)
                P[r0 + i][c0 + j] = s[i][j] * scale;
    }
    __syncthreads();

    {
        const int wid = tid >> 6, lane = tid & 63;
        for (int r = wid; r < T_; r += 4) {
            float x0 = P[r][lane];
            float x1 = (lane < 32) ? P[r][64 + lane] : -INFINITY;
            float m = fmaxf(x0, x1);
            #pragma unroll
            for (int off = 32; off > 0; off >>= 1) m = fmaxf(m, __shfl_xor(m, off));
            float e0 = expf(x0 - m);
            float e1 = (lane < 32) ? expf(x1 - m) : 0.f;
            float ssum = e0 + e1;
            #pragma unroll
            for (int off = 32; off > 0; off >>= 1) ssum += __shfl_xor(ssum, off);
            float inv = 1.0f / ssum;
            P[r][lane] = e0 * inv;
            if (lane < 32) P[r][64 + lane] = e1 * inv;
        }
    }
    __syncthreads();

    {
        float o[6][2];
        #pragma unroll
        for (int i = 0; i < 6; i++) { o[i][0] = 0.f; o[i][1] = 0.f; }
        const int c2 = tx * 2;
        for (int kk = 0; kk < T_; kk++) {
            float v0 = Vs[kk][c2], v1 = Vs[kk][c2 + 1];
            #pragma unroll
            for (int i = 0; i < 6; i++) {
                float p = P[r0 + i][kk];
                o[i][0] += p * v0;
                o[i][1] += p * v1;
            }
        }
        const int bn = g >> 3, h = g & 7;
        float* aob = ao + ((size_t)bn * T_) * D_ + h * HD_;
        #pragma unroll
        for (int i = 0; i < 6; i++) {
            aob[(r0 + i) * D_ + c2 + 0] = o[i][0];
            aob[(r0 + i) * D_ + c2 + 1] = o[i][1];
        }
    }
}

// ---------------------------------------------------------------------------
// Kernel 3: out = out @ Wo^T + bo, IN-PLACE on d_out, split-bf16 MFMA.
// BM=128, BN=256 (full width -> race-free in-place), BK=32, 512 thr = 8 waves
// (2 rows x 4 cols of 64x64).
// ---------------------------------------------------------------------------
__global__ __launch_bounds__(512)
void wo_kernel(const float* __restrict__ Wo, const float* __restrict__ bo,
               float* __restrict__ io)
{
    const int tid  = threadIdx.x;
    const int row0 = blockIdx.x * 128;
    const int lane = tid & 63;
    const int w    = tid >> 6;        // 0..7
    const int wr   = w >> 2;          // 0..1
    const int wc   = w & 3;           // 0..3
    const int lr   = lane & 15;
    const int kgl  = lane >> 4;

    __shared__ __align__(16) uint Ah[4*128*4];   // 8 KB
    __shared__ __align__(16) uint Al[4*128*4];
    __shared__ __align__(16) uint Bh[4*256*4];   // 16 KB
    __shared__ __align__(16) uint Bl[4*256*4];

    f32x4 acc[4][4];
    #pragma unroll
    for (int m = 0; m < 4; m++)
        #pragma unroll
        for (int n = 0; n < 4; n++) acc[m][n] = (f32x4)0.f;

    for (int k0 = 0; k0 < D_; k0 += 32) {
        {   // A: 512 chunks, 1/thread
            const int kg = tid >> 7;
            const int r  = tid & 127;
            const float* pa = io + (size_t)(row0 + r) * D_ + k0 + kg * 8;
            float4 a0 = *(const float4*)pa;
            float4 a1 = *(const float4*)(pa + 4);
            uint4 h, l;
            split8(a0, a1, h, l);
            *(uint4*)&Ah[(kg*128 + r)*4] = h;
            *(uint4*)&Al[(kg*128 + r)*4] = l;
        }
        #pragma unroll
        for (int i = 0; i < 2; i++) {   // B: 1024 chunks, 2/thread
            const int c  = tid + i * 512;
            const int kg = c >> 8;
            const int r  = c & 255;
            const float* pb = Wo + (size_t)r * D_ + k0 + kg * 8;
            float4 b0 = *(const float4*)pb;
            float4 b1 = *(const float4*)(pb + 4);
            uint4 h, l;
            split8(b0, b1, h, l);
            *(uint4*)&Bh[(kg*256 + r)*4] = h;
            *(uint4*)&Bl[(kg*256 + r)*4] = l;
        }
        __syncthreads();

        bf16x8 ah[4], al[4], bh[4], bl[4];
        #pragma unroll
        for (int m = 0; m < 4; m++) {
            const int ra = wr*64 + m*16 + lr;
            ah[m] = *(const bf16x8*)&Ah[(kgl*128 + ra)*4];
            al[m] = *(const bf16x8*)&Al[(kgl*128 + ra)*4];
        }
        #pragma unroll
        for (int n = 0; n < 4; n++) {
            const int cb = wc*64 + n*16 + lr;
            bh[n] = *(const bf16x8*)&Bh[(kgl*256 + cb)*4];
            bl[n] = *(const bf16x8*)&Bl[(kgl*256 + cb)*4];
        }
        #pragma unroll
        for (int m = 0; m < 4; m++)
            #pragma unroll
            for (int n = 0; n < 4; n++) {
                acc[m][n] = __builtin_amdgcn_mfma_f32_16x16x32_bf16(ah[m], bl[n], acc[m][n], 0, 0, 0);
                acc[m][n] = __builtin_amdgcn_mfma_f32_16x16x32_bf16(al[m], bh[n], acc[m][n], 0, 0, 0);
                acc[m][n] = __builtin_amdgcn_mfma_f32_16x16x32_bf16(ah[m], bh[n], acc[m][n], 0, 0, 0);
            }
        __syncthreads();
    }

    #pragma unroll
    for (int n = 0; n < 4; n++) {
        const int gcol = wc*64 + n*16 + lr;
        const float bv = bo[gcol];
        #pragma unroll
        for (int m = 0; m < 4; m++) {
            #pragma unroll
            for (int reg = 0; reg < 4; reg++) {
                const int grow = row0 + wr*64 + m*16 + kgl*4 + reg;
                io[(size_t)grow * D_ + gcol] = acc[m][n][reg] + bv;
            }
        }
    }
}

// ---------------------------------------------------------------------------
extern "C" void kernel_launch(void* const* d_in, const int* in_sizes, int n_in,
                              void* d_out, int out_size, void* d_ws, size_t ws_size,
                              hipStream_t stream)
{
    const float* query = (const float*)d_in[0];
    const float* key   = (const float*)d_in[1];
    const float* value = (const float*)d_in[2];
    // d_in[3..5]: pattern_matrix, Wp, bp -- mathematically a no-op (mask == 1)
    const float* Wq = (const float*)d_in[6];
    const float* bq = (const float*)d_in[7];
    const float* Wk = (const float*)d_in[8];
    const float* bk = (const float*)d_in[9];
    const float* Wv = (const float*)d_in[10];
    const float* bv = (const float*)d_in[11];
    const float* Wo = (const float*)d_in[12];
    const float* bo = (const float*)d_in[13];

    float* out = (float*)d_out;
    float* ws  = (float*)d_ws;
    float* qb  = ws;               // head-split (bn,h,t,hd)
    float* kb  = ws + (size_t)QSZ;
    float* vb  = ws + (size_t)QSZ * 2;   // needs 200.5 MB of ws

    proj_kernel<<<dim3(R_ / 128, D_ / 128, 3), 256, 0, stream>>>(
        query, key, value, Wq, Wk, Wv, bq, bk, bv, qb, kb, vb);
    attn_kernel<<<dim3(G_), 256, 0, stream>>>(qb, kb, vb, out);
    wo_kernel<<<dim3(R_ / 128), 512, 0, stream>>>(Wo, bo, out);
}

// Round 3
// 250.256 us; speedup vs baseline: 2.7376x; 1.9529x over previous
//
#include <hip/hip_runtime.h>
#include <math.h>

// Problem constants
#define B_  4
#define N_  170
#define T_  96
#define D_  256
#define H_  8
#define HD_ 32
#define R_  (B_*N_*T_)    // 65280 rows
#define G_  (B_*N_*H_)    // 5440 attention groups
#define GSZ (T_*HD_)      // 3072 elements per group per tensor
#define QSZ (R_*D_)       // 16,711,680 elements per q/k/v buffer (now bf16)

typedef short  bf16x8 __attribute__((ext_vector_type(8)));
typedef float  f32x4  __attribute__((ext_vector_type(4)));

__device__ __forceinline__ ushort to_bf16(float x)
{
    uint u = __builtin_bit_cast(uint, x);
    u += 0x8000u;                      // round-half-up (bias ~2^-17, negligible)
    return (ushort)(u >> 16);
}

// split one fp32 pair into packed bf16 hi-word and lo-word (element0 in low 16)
__device__ __forceinline__ void split2(float x0, float x1, uint& hi, uint& lo)
{
    uint u0 = __builtin_bit_cast(uint, x0);
    uint u1 = __builtin_bit_cast(uint, x1);
    hi = (u0 >> 16) | (u1 & 0xFFFF0000u);
    float h0 = __builtin_bit_cast(float, u0 & 0xFFFF0000u);
    float h1 = __builtin_bit_cast(float, u1 & 0xFFFF0000u);
    float l0 = x0 - h0, l1 = x1 - h1;
    uint v0 = __builtin_bit_cast(uint, l0);
    uint v1 = __builtin_bit_cast(uint, l1);
    lo = (v0 >> 16) | (v1 & 0xFFFF0000u);
}

__device__ __forceinline__ void split8(float4 a0, float4 a1, uint4& hi, uint4& lo)
{
    split2(a0.x, a0.y, hi.x, lo.x);
    split2(a0.z, a0.w, hi.y, lo.y);
    split2(a1.x, a1.y, hi.z, lo.z);
    split2(a1.z, a1.w, hi.w, lo.w);
}

// ---------------------------------------------------------------------------
// Kernel 1: fused Q/K/V projection via split-bf16 MFMA.
// q,k out: bf16 [g][t][hd] (q has 1/sqrt(32) folded in); v out: bf16 [g][hd][t].
// ---------------------------------------------------------------------------
__global__ __launch_bounds__(256)
void proj_kernel(const float* __restrict__ Xq, const float* __restrict__ Xk,
                 const float* __restrict__ Xv,
                 const float* __restrict__ Wq, const float* __restrict__ Wk,
                 const float* __restrict__ Wv,
                 const float* __restrict__ bq, const float* __restrict__ bk,
                 const float* __restrict__ bv,
                 ushort* __restrict__ oq, ushort* __restrict__ ok_,
                 ushort* __restrict__ ov)
{
    const int z = blockIdx.z;
    const float* X    = (z == 0) ? Xq : (z == 1) ? Xk : Xv;
    const float* W    = (z == 0) ? Wq : (z == 1) ? Wk : Wv;
    const float* bias = (z == 0) ? bq : (z == 1) ? bk : bv;
    ushort*      out  = (z == 0) ? oq : (z == 1) ? ok_ : ov;

    const int tid  = threadIdx.x;
    const int row0 = blockIdx.x * 128;
    const int col0 = blockIdx.y * 128;
    const int lane = tid & 63;
    const int w    = tid >> 6;
    const int wr   = w >> 1;
    const int wc   = w & 1;
    const int lr   = lane & 15;
    const int kgl  = lane >> 4;

    __shared__ __align__(16) uint Ah[4*128*4];
    __shared__ __align__(16) uint Al[4*128*4];
    __shared__ __align__(16) uint Bh[4*128*4];
    __shared__ __align__(16) uint Bl[4*128*4];

    f32x4 acc[4][4];
    #pragma unroll
    for (int m = 0; m < 4; m++)
        #pragma unroll
        for (int n = 0; n < 4; n++) acc[m][n] = (f32x4)0.f;

    for (int k0 = 0; k0 < D_; k0 += 32) {
        #pragma unroll
        for (int i = 0; i < 2; i++) {
            const int c  = tid + i * 256;
            const int kg = c >> 7;
            const int r  = c & 127;
            const float* pa = X + (size_t)(row0 + r) * D_ + k0 + kg * 8;
            float4 a0 = *(const float4*)pa;
            float4 a1 = *(const float4*)(pa + 4);
            uint4 h, l;
            split8(a0, a1, h, l);
            *(uint4*)&Ah[(kg*128 + r)*4] = h;
            *(uint4*)&Al[(kg*128 + r)*4] = l;
            const float* pb = W + (size_t)(col0 + r) * D_ + k0 + kg * 8;
            float4 b0 = *(const float4*)pb;
            float4 b1 = *(const float4*)(pb + 4);
            split8(b0, b1, h, l);
            *(uint4*)&Bh[(kg*128 + r)*4] = h;
            *(uint4*)&Bl[(kg*128 + r)*4] = l;
        }
        __syncthreads();

        bf16x8 ah[4], al[4], bh[4], bl[4];
        #pragma unroll
        for (int m = 0; m < 4; m++) {
            const int ra = wr*64 + m*16 + lr;
            ah[m] = *(const bf16x8*)&Ah[(kgl*128 + ra)*4];
            al[m] = *(const bf16x8*)&Al[(kgl*128 + ra)*4];
        }
        #pragma unroll
        for (int n = 0; n < 4; n++) {
            const int cb = wc*64 + n*16 + lr;
            bh[n] = *(const bf16x8*)&Bh[(kgl*128 + cb)*4];
            bl[n] = *(const bf16x8*)&Bl[(kgl*128 + cb)*4];
        }
        #pragma unroll
        for (int m = 0; m < 4; m++)
            #pragma unroll
            for (int n = 0; n < 4; n++) {
                acc[m][n] = __builtin_amdgcn_mfma_f32_16x16x32_bf16(ah[m], bl[n], acc[m][n], 0, 0, 0);
                acc[m][n] = __builtin_amdgcn_mfma_f32_16x16x32_bf16(al[m], bh[n], acc[m][n], 0, 0, 0);
                acc[m][n] = __builtin_amdgcn_mfma_f32_16x16x32_bf16(ah[m], bh[n], acc[m][n], 0, 0, 0);
            }
        __syncthreads();
    }

    // epilogue: bias (+scale for q) -> bf16, head-split store
    const float sc = (z == 0) ? 0.17677669529663687f : 1.0f;
    if (z < 2) {
        // q,k: [g][t][hd]
        #pragma unroll
        for (int n = 0; n < 4; n++) {
            const int gcol = col0 + wc*64 + n*16 + lr;
            const int h    = gcol >> 5;
            const int hd   = gcol & 31;
            const float bv = bias[gcol];
            #pragma unroll
            for (int m = 0; m < 4; m++) {
                #pragma unroll
                for (int reg = 0; reg < 4; reg++) {
                    const int grow = row0 + wr*64 + m*16 + kgl*4 + reg;
                    const int bn = grow / T_;
                    const int t  = grow - bn * T_;
                    out[(size_t)((bn*H_ + h)*T_ + t)*HD_ + hd] = to_bf16((acc[m][n][reg] + bv) * sc);
                }
            }
        }
    } else {
        // v: [g][hd][t], pack 4 consecutive t (reg dim) into ushort4
        #pragma unroll
        for (int n = 0; n < 4; n++) {
            const int gcol = col0 + wc*64 + n*16 + lr;
            const int h    = gcol >> 5;
            const int hd   = gcol & 31;
            const float bv = bias[gcol];
            #pragma unroll
            for (int m = 0; m < 4; m++) {
                const int grow0 = row0 + wr*64 + m*16 + kgl*4;  // 4-aligned, stays in one bn
                const int bn = grow0 / T_;
                const int t0 = grow0 - bn * T_;
                ushort4 pk;
                pk.x = to_bf16(acc[m][n][0] + bv);
                pk.y = to_bf16(acc[m][n][1] + bv);
                pk.z = to_bf16(acc[m][n][2] + bv);
                pk.w = to_bf16(acc[m][n][3] + bv);
                *(ushort4*)&out[(size_t)((bn*H_ + h)*HD_ + hd)*T_ + t0] = pk;
            }
        }
    }
}

// ---------------------------------------------------------------------------
// Kernel 2: MFMA attention. One block per (bn,h) group, 384 thr = 6 waves,
// wave w owns query rows [16w,16w+16). Softmax in-register via lane butterfly.
// LDS planes: 16B rows, plane strides = 8 banks offset (1568B / 544B).
//   Q: off 0,      4 planes x 1568B   (plane kg, row t)
//   K: off 6272,   4 planes x 1568B
//   V: off 12544, 12 planes x 544B    (plane ks*4+kg, row hd)   [v is [hd][t]]
//   P: off 19072, 12 planes x 1568B   (plane ks*4+kg, row q)
// ---------------------------------------------------------------------------
__global__ __launch_bounds__(384)
void attn_kernel(const ushort* __restrict__ q, const ushort* __restrict__ k,
                 const ushort* __restrict__ vt, float* __restrict__ ao)
{
    const int g   = blockIdx.x;
    const int tid = threadIdx.x;
    __shared__ __align__(16) char lds[37888];

    // ---- stage Q,K,V (each 384 x 16B chunks, fully coalesced) ----
    {
        const ushort* Qg = q  + (size_t)g * GSZ;
        const ushort* Kg = k  + (size_t)g * GSZ;
        const ushort* Vg = vt + (size_t)g * GSZ;
        const int t  = tid >> 2, kg = tid & 3;
        uint4 aq = *(const uint4*)(Qg + tid * 8);
        *(uint4*)(lds + kg*1568 + t*16) = aq;
        uint4 ak = *(const uint4*)(Kg + tid * 8);
        *(uint4*)(lds + 6272 + kg*1568 + t*16) = ak;
        const int hd = tid / 12, pl = tid - hd*12;
        uint4 av = *(const uint4*)(Vg + tid * 8);
        *(uint4*)(lds + 12544 + pl*544 + hd*16) = av;
    }
    __syncthreads();

    const int w = tid >> 6, lane = tid & 63;
    const int lr = lane & 15, kgl = lane >> 4;

    // ---- QK^T: S[16 rows][96 cols], scale already folded into q ----
    f32x4 acc[6];
    {
        bf16x8 aq = *(const bf16x8*)(lds + kgl*1568 + (w*16 + lr)*16);
        #pragma unroll
        for (int n = 0; n < 6; n++) {
            bf16x8 bk = *(const bf16x8*)(lds + 6272 + kgl*1568 + (n*16 + lr)*16);
            acc[n] = __builtin_amdgcn_mfma_f32_16x16x32_bf16(aq, bk, (f32x4)0.f, 0, 0, 0);
        }
    }

    // ---- softmax in-register: row r = w*16 + kgl*4 + reg, col = n*16 + lr ----
    float mx[4], sm[4], inv[4];
    #pragma unroll
    for (int reg = 0; reg < 4; reg++) {
        float m = acc[0][reg];
        #pragma unroll
        for (int n = 1; n < 6; n++) m = fmaxf(m, acc[n][reg]);
        mx[reg] = m;
    }
    #pragma unroll
    for (int off = 1; off < 16; off <<= 1)
        #pragma unroll
        for (int reg = 0; reg < 4; reg++)
            mx[reg] = fmaxf(mx[reg], __shfl_xor(mx[reg], off));
    #pragma unroll
    for (int reg = 0; reg < 4; reg++) sm[reg] = 0.f;
    #pragma unroll
    for (int n = 0; n < 6; n++)
        #pragma unroll
        for (int reg = 0; reg < 4; reg++) {
            float e = __expf(acc[n][reg] - mx[reg]);
            acc[n][reg] = e;
            sm[reg] += e;
        }
    #pragma unroll
    for (int off = 1; off < 16; off <<= 1)
        #pragma unroll
        for (int reg = 0; reg < 4; reg++)
            sm[reg] += __shfl_xor(sm[reg], off);
    #pragma unroll
    for (int reg = 0; reg < 4; reg++) inv[reg] = 1.0f / sm[reg];

    // ---- P -> bf16 -> LDS fragment planes (wave-local rows only) ----
    #pragma unroll
    for (int n = 0; n < 6; n++) {
        const int pl = (n >> 1)*4 + ((n*2 + (lr >> 3)) & 3);   // plane ks*4+kgw
        const int j  = lr & 7;
        #pragma unroll
        for (int reg = 0; reg < 4; reg++) {
            const int row = w*16 + kgl*4 + reg;
            *(ushort*)(lds + 19072 + pl*1568 + row*16 + j*2) =
                to_bf16(acc[n][reg] * inv[reg]);
        }
    }
    __syncthreads();

    // ---- O = P @ V^T : 2 col tiles (hd 0-15,16-31), K = 96 (3 steps) ----
    f32x4 o[2] = {(f32x4)0.f, (f32x4)0.f};
    #pragma unroll
    for (int ks = 0; ks < 3; ks++) {
        bf16x8 ap = *(const bf16x8*)(lds + 19072 + (ks*4 + kgl)*1568 + (w*16 + lr)*16);
        #pragma unroll
        for (int n2 = 0; n2 < 2; n2++) {
            bf16x8 bv = *(const bf16x8*)(lds + 12544 + (ks*4 + kgl)*544 + (n2*16 + lr)*16);
            o[n2] = __builtin_amdgcn_mfma_f32_16x16x32_bf16(ap, bv, o[n2], 0, 0, 0);
        }
    }

    // ---- store to ao (f32, [bn][t][D]): row q on (kgl,reg), col hd on (n2,lr) ----
    const int bn = g >> 3, h = g & 7;
    float* base = ao + (size_t)(bn * T_) * D_ + h * HD_;
    #pragma unroll
    for (int n2 = 0; n2 < 2; n2++)
        #pragma unroll
        for (int reg = 0; reg < 4; reg++) {
            const int qr = w*16 + kgl*4 + reg;
            base[(size_t)qr * D_ + n2*16 + lr] = o[n2][reg];
        }
}

// ---------------------------------------------------------------------------
// Kernel 3: out = out @ Wo^T + bo, IN-PLACE on d_out, split-bf16 MFMA.
// ---------------------------------------------------------------------------
__global__ __launch_bounds__(512)
void wo_kernel(const float* __restrict__ Wo, const float* __restrict__ bo,
               float* __restrict__ io)
{
    const int tid  = threadIdx.x;
    const int row0 = blockIdx.x * 128;
    const int lane = tid & 63;
    const int w    = tid >> 6;
    const int wr   = w >> 2;
    const int wc   = w & 3;
    const int lr   = lane & 15;
    const int kgl  = lane >> 4;

    __shared__ __align__(16) uint Ah[4*128*4];
    __shared__ __align__(16) uint Al[4*128*4];
    __shared__ __align__(16) uint Bh[4*256*4];
    __shared__ __align__(16) uint Bl[4*256*4];

    f32x4 acc[4][4];
    #pragma unroll
    for (int m = 0; m < 4; m++)
        #pragma unroll
        for (int n = 0; n < 4; n++) acc[m][n] = (f32x4)0.f;

    for (int k0 = 0; k0 < D_; k0 += 32) {
        {
            const int kg = tid >> 7;
            const int r  = tid & 127;
            const float* pa = io + (size_t)(row0 + r) * D_ + k0 + kg * 8;
            float4 a0 = *(const float4*)pa;
            float4 a1 = *(const float4*)(pa + 4);
            uint4 h, l;
            split8(a0, a1, h, l);
            *(uint4*)&Ah[(kg*128 + r)*4] = h;
            *(uint4*)&Al[(kg*128 + r)*4] = l;
        }
        #pragma unroll
        for (int i = 0; i < 2; i++) {
            const int c  = tid + i * 512;
            const int kg = c >> 8;
            const int r  = c & 255;
            const float* pb = Wo + (size_t)r * D_ + k0 + kg * 8;
            float4 b0 = *(const float4*)pb;
            float4 b1 = *(const float4*)(pb + 4);
            uint4 h, l;
            split8(b0, b1, h, l);
            *(uint4*)&Bh[(kg*256 + r)*4] = h;
            *(uint4*)&Bl[(kg*256 + r)*4] = l;
        }
        __syncthreads();

        bf16x8 ah[4], al[4], bh[4], bl[4];
        #pragma unroll
        for (int m = 0; m < 4; m++) {
            const int ra = wr*64 + m*16 + lr;
            ah[m] = *(const bf16x8*)&Ah[(kgl*128 + ra)*4];
            al[m] = *(const bf16x8*)&Al[(kgl*128 + ra)*4];
        }
        #pragma unroll
        for (int n = 0; n < 4; n++) {
            const int cb = wc*64 + n*16 + lr;
            bh[n] = *(const bf16x8*)&Bh[(kgl*256 + cb)*4];
            bl[n] = *(const bf16x8*)&Bl[(kgl*256 + cb)*4];
        }
        #pragma unroll
        for (int m = 0; m < 4; m++)
            #pragma unroll
            for (int n = 0; n < 4; n++) {
                acc[m][n] = __builtin_amdgcn_mfma_f32_16x16x32_bf16(ah[m], bl[n], acc[m][n], 0, 0, 0);
                acc[m][n] = __builtin_amdgcn_mfma_f32_16x16x32_bf16(al[m], bh[n], acc[m][n], 0, 0, 0);
                acc[m][n] = __builtin_amdgcn_mfma_f32_16x16x32_bf16(ah[m], bh[n], acc[m][n], 0, 0, 0);
            }
        __syncthreads();
    }

    #pragma unroll
    for (int n = 0; n < 4; n++) {
        const int gcol = wc*64 + n*16 + lr;
        const float bv = bo[gcol];
        #pragma unroll
        for (int m = 0; m < 4; m++) {
            #pragma unroll
            for (int reg = 0; reg < 4; reg++) {
                const int grow = row0 + wr*64 + m*16 + kgl*4 + reg;
                io[(size_t)grow * D_ + gcol] = acc[m][n][reg] + bv;
            }
        }
    }
}

// ---------------------------------------------------------------------------
extern "C" void kernel_launch(void* const* d_in, const int* in_sizes, int n_in,
                              void* d_out, int out_size, void* d_ws, size_t ws_size,
                              hipStream_t stream)
{
    const float* query = (const float*)d_in[0];
    const float* key   = (const float*)d_in[1];
    const float* value = (const float*)d_in[2];
    // d_in[3..5]: pattern_matrix, Wp, bp -- mathematically a no-op (mask == 1)
    const float* Wq = (const float*)d_in[6];
    const float* bq = (const float*)d_in[7];
    const float* Wk = (const float*)d_in[8];
    const float* bk = (const float*)d_in[9];
    const float* Wv = (const float*)d_in[10];
    const float* bv = (const float*)d_in[11];
    const float* Wo = (const float*)d_in[12];
    const float* bo = (const float*)d_in[13];

    float*  out = (float*)d_out;
    ushort* ws  = (ushort*)d_ws;
    ushort* qb  = ws;                      // bf16 head-split [g][t][hd], scaled
    ushort* kb  = ws + (size_t)QSZ;        // bf16 [g][t][hd]
    ushort* vb  = ws + (size_t)QSZ * 2;    // bf16 transposed [g][hd][t]; 100 MB total

    proj_kernel<<<dim3(R_ / 128, D_ / 128, 3), 256, 0, stream>>>(
        query, key, value, Wq, Wk, Wv, bq, bk, bv, qb, kb, vb);
    attn_kernel<<<dim3(G_), 384, 0, stream>>>(qb, kb, vb, out);
    wo_kernel<<<dim3(R_ / 128), 512, 0, stream>>>(Wo, bo, out);
}